// Round 13
// baseline (2517.595 us; speedup 1.0000x reference)
//
#include <hip/hip_runtime.h>
#include <math.h>

#define NB 8
#define HH 52
#define WW 52
#define LL 2704
#define CC 256
#define HC 26
#define WC 26
#define SS 676
#define C2 512
#define FCn 8
#define SCn 32
#define M16 (NB*LL)     // 21632
#define M32 (NB*SS)     // 5408
#define KCONV (9*C2)    // 4608
#define SAMP16 ((size_t)LL*CC)
#define SAMP32 ((size_t)SS*CC)

typedef double dvec4 __attribute__((ext_vector_type(4)));
typedef float  f32x4 __attribute__((ext_vector_type(4)));
typedef short  b16x8 __attribute__((ext_vector_type(8)));

__device__ __forceinline__ float  gelu_ct(float x){ return 0.5f*x*(1.0f + erff(x*0.70710678118654752f)); }
__device__ __forceinline__ double gelu_ct(double x){ return 0.5*x*(1.0 + erf(x*0.70710678118654752440)); }

__device__ __forceinline__ short f2b(float x){
    union { float f; unsigned u; } v; v.f = x;
    unsigned r = v.u + 0x7fffu + ((v.u >> 16) & 1u);
    return (short)(r >> 16);
}

// ================= f64 MFMA GEMM v4: BM=128, BK=16, reg-prefetch ========================
// Out = [gelu]( A0 @ W + [bias] + [bilerp(cw)] ); A0 (M,K) row-major, W (K,N) f32.
template<typename TA0, typename TO, bool GELU, bool ADDB, bool UPS>
__global__ __launch_bounds__(256) void gemm_d64(
    const TA0* __restrict__ A0,
    const float* __restrict__ W, const float* __restrict__ Bias,
    const double* __restrict__ cw,
    TO* __restrict__ Out, int M, int K, int N)
{
    __shared__ double As[16][130];
    __shared__ double Bs[16][66];
    const int t = threadIdx.x;
    const int mBase = blockIdx.y * 128;
    const int nBase = blockIdx.x * 64;
    const int arow = t >> 1;
    const int kofA = (t & 1) << 3;
    const int kb   = t >> 4;
    const int nof  = (t & 15) << 2;
    const int w  = t >> 6;
    const int lane = t & 63;
    const int lr = lane & 15, lk = lane >> 4;

    dvec4 prm = {0.,0.,0.,0.}, prn = {0.,0.,0.,0.};
    prm = __builtin_amdgcn_mfma_f64_16x16x4f64((double)lr, 0.25, prm, 0,0,0);
    prn = __builtin_amdgcn_mfma_f64_16x16x4f64(0.25, (double)lr, prn, 0,0,0);
    int pm[4], pn[4];
    #pragma unroll
    for (int i=0;i<4;i++){ pm[i] = (int)prm[i]; pn[i] = (int)prn[i]; }

    dvec4 acc[2][4];
    #pragma unroll
    for (int rf=0;rf<2;rf++)
        #pragma unroll
        for (int cb=0;cb<4;cb++) acc[rf][cb] = (dvec4){0.,0.,0.,0.};

    const int am = mBase + arow;
    double aReg[8], bReg[4];
    auto loadA = [&](int k0){
        #pragma unroll
        for (int j=0;j<8;j++){
            int k = k0 + kofA + j;
            aReg[j] = (am < M) ? (double)A0[(size_t)am*K + k] : 0.0;
        }
    };
    auto loadB = [&](int k0){
        #pragma unroll
        for (int j=0;j<4;j++)
            bReg[j] = (double)W[(size_t)(k0+kb)*N + nBase + nof + j];
    };
    loadA(0); loadB(0);
    for (int k0 = 0; k0 < K; k0 += 16){
        __syncthreads();
        #pragma unroll
        for (int j=0;j<8;j++) As[kofA+j][arow] = aReg[j];
        #pragma unroll
        for (int j=0;j<4;j++) Bs[kb][nof+j] = bReg[j];
        __syncthreads();
        if (k0 + 16 < K){ loadA(k0+16); loadB(k0+16); }
        #pragma unroll
        for (int ks = 0; ks < 4; ks++){
            double a0 = As[ks*4+lk][w*32 + lr];
            double a1 = As[ks*4+lk][w*32 + 16 + lr];
            double b0 = Bs[ks*4+lk][lr];
            double b1 = Bs[ks*4+lk][16 + lr];
            double b2 = Bs[ks*4+lk][32 + lr];
            double b3 = Bs[ks*4+lk][48 + lr];
            acc[0][0] = __builtin_amdgcn_mfma_f64_16x16x4f64(a0,b0,acc[0][0],0,0,0);
            acc[0][1] = __builtin_amdgcn_mfma_f64_16x16x4f64(a0,b1,acc[0][1],0,0,0);
            acc[0][2] = __builtin_amdgcn_mfma_f64_16x16x4f64(a0,b2,acc[0][2],0,0,0);
            acc[0][3] = __builtin_amdgcn_mfma_f64_16x16x4f64(a0,b3,acc[0][3],0,0,0);
            acc[1][0] = __builtin_amdgcn_mfma_f64_16x16x4f64(a1,b0,acc[1][0],0,0,0);
            acc[1][1] = __builtin_amdgcn_mfma_f64_16x16x4f64(a1,b1,acc[1][1],0,0,0);
            acc[1][2] = __builtin_amdgcn_mfma_f64_16x16x4f64(a1,b2,acc[1][2],0,0,0);
            acc[1][3] = __builtin_amdgcn_mfma_f64_16x16x4f64(a1,b3,acc[1][3],0,0,0);
        }
    }
    #pragma unroll
    for (int rf=0;rf<2;rf++){
        #pragma unroll
        for (int i=0;i<4;i++){
            const int row = mBase + w*32 + rf*16 + pm[i];
            if (row >= M) continue;
            int nloc = 0, y0=0, y1=0, x0=0, x1=0;
            double dy=0.0, dx=0.0;
            if (UPS){
                nloc = row / LL;
                int l = row - nloc*LL;
                int hh = l / WW, ww2 = l - hh*WW;
                double fy = (hh==HH-1) ? (double)(HC-1) : hh*((double)(HC-1)/(HH-1));
                double fx = (ww2==WW-1) ? (double)(WC-1) : ww2*((double)(WC-1)/(WW-1));
                y0 = (int)fy; y1 = min(y0+1, HC-1);
                x0 = (int)fx; x1 = min(x0+1, WC-1);
                dy = fy - y0; dx = fx - x0;
            }
            #pragma unroll
            for (int cb=0;cb<4;cb++){
                const int col = nBase + cb*16 + pn[i];
                double v = acc[rf][cb][i];
                if (UPS){
                    const double* cb0 = cw + ((size_t)nloc*SS)*N + col;
                    double v00 = cb0[(size_t)(y0*WC + x0)*N];
                    double v01 = cb0[(size_t)(y0*WC + x1)*N];
                    double v10 = cb0[(size_t)(y1*WC + x0)*N];
                    double v11 = cb0[(size_t)(y1*WC + x1)*N];
                    double r0 = v00*(1.0-dy) + v10*dy;
                    double r1 = v01*(1.0-dy) + v11*dy;
                    v += r0*(1.0-dx) + r1*dx;
                }
                if (ADDB) v += (double)Bias[col];
                if (GELU) v = gelu_ct(v);
                Out[(size_t)row*N + col] = (TO)v;
            }
        }
    }
}

// ================= bf16 MFMA GEMM, bf16 A-inputs (post-argmax path) =====================
template<bool GELU, bool CAT, bool OUT_BF>
__global__ __launch_bounds__(256) void gemm_bf(
    const short* __restrict__ A0, const short* __restrict__ A1, int K0,
    const short* __restrict__ Wb, const float* __restrict__ Bias,
    void* __restrict__ OutV, int M, int K, int N)
{
    __shared__ short As[64][72];
    __shared__ short Bs[64][72];
    const int t = threadIdx.x;
    const int mBase = blockIdx.y*64, nBase = blockIdx.x*64;
    const int lane = t & 63, lr = lane & 15, lg = lane >> 4;
    const int wr = (t >> 6) * 16;
    const int srow = t >> 2;
    const int sk   = (t & 3) * 16;
    const int am = mBase + srow;
    const int bo = nBase + srow;
    f32x4 acc[4] = {{0,0,0,0},{0,0,0,0},{0,0,0,0},{0,0,0,0}};

    for (int c0 = 0; c0 < K; c0 += 64){
        const int kk = c0 + sk;
        const short* ap;
        if (!CAT || kk < K0) ap = A0 + (size_t)am*K0 + kk;
        else                 ap = A1 + (size_t)am*(K-K0) + (kk - K0);
        b16x8 a0 = *(const b16x8*)ap;
        b16x8 a1 = *(const b16x8*)(ap + 8);
        b16x8 bv0 = *(const b16x8*)&Wb[(size_t)bo*K + kk];
        b16x8 bv1 = *(const b16x8*)&Wb[(size_t)bo*K + kk + 8];
        __syncthreads();
        *(b16x8*)&As[srow][sk]     = a0;
        *(b16x8*)&As[srow][sk + 8] = a1;
        *(b16x8*)&Bs[srow][sk]     = bv0;
        *(b16x8*)&Bs[srow][sk + 8] = bv1;
        __syncthreads();
        #pragma unroll
        for (int kc=0;kc<2;kc++){
            b16x8 a = *(const b16x8*)&As[wr + lr][kc*32 + lg*8];
            #pragma unroll
            for (int cb=0;cb<4;cb++){
                b16x8 b = *(const b16x8*)&Bs[cb*16 + lr][kc*32 + lg*8];
                acc[cb] = __builtin_amdgcn_mfma_f32_16x16x32_bf16(a, b, acc[cb], 0,0,0);
            }
        }
    }
    #pragma unroll
    for (int cb=0;cb<4;cb++){
        int col = nBase + cb*16 + lr;
        float bias = Bias[col];
        #pragma unroll
        for (int i=0;i<4;i++){
            int row = mBase + wr + lg*4 + i;
            float v = acc[cb][i] + bias;
            if (GELU) v = gelu_ct(v);
            if (OUT_BF) ((short*)OutV)[(size_t)row*N + col] = f2b(v);
            else        ((float*)OutV)[(size_t)row*N + col] = v;
        }
    }
}

// ================= 3x3 conv, bf16 MFMA, M-tile 32 x N=256; grid = 676 ===================
__global__ __launch_bounds__(256) void conv_bf2(const short* __restrict__ Xb,
    const short* __restrict__ WTb, const float* __restrict__ Bias, float* __restrict__ Out)
{
    __shared__ short As[32][72];
    __shared__ short Bs[256][72];
    const int t = threadIdx.x;
    const int mBase = blockIdx.x*32;
    const int lane = t & 63, lr = lane & 15, lg = lane >> 4;
    const int w = t >> 6;
    const int wr16 = (w & 1) * 16;
    const int ch   = (w >> 1) * 8;
    const int arow = t >> 3;
    const int ska  = (t & 7) * 8;
    const int srow = t >> 2;
    const int sk   = (t & 3) * 16;
    const int am = mBase + arow;
    const int an = am / LL; const int ahw = am % LL;
    const int ah = ahw / WW; const int aw = ahw % WW;
    f32x4 acc[8];
    #pragma unroll
    for (int i=0;i<8;i++) acc[i] = (f32x4){0.f,0.f,0.f,0.f};
    const b16x8 z = {0,0,0,0,0,0,0,0};

    for (int pos = 0; pos < 9; pos++){
        const int dh = pos/3 - 1, dw = pos%3 - 1;
        const int h2 = ah + dh, w2 = aw + dw;
        const bool ok = (h2 >= 0 && h2 < HH && w2 >= 0 && w2 < WW);
        const short* xrow = Xb + ((size_t)(an*LL + h2*WW + w2))*C2;
        for (int c0 = 0; c0 < C2; c0 += 64){
            b16x8 a0 = ok ? *(const b16x8*)&xrow[c0 + ska] : z;
            b16x8 w0[4], w1[4];
            #pragma unroll
            for (int r=0;r<4;r++){
                const short* wp = WTb + (size_t)(srow + 64*r)*KCONV + pos*C2 + c0 + sk;
                w0[r] = *(const b16x8*)wp;
                w1[r] = *(const b16x8*)(wp + 8);
            }
            __syncthreads();
            *(b16x8*)&As[arow][ska] = a0;
            #pragma unroll
            for (int r=0;r<4;r++){
                *(b16x8*)&Bs[srow + 64*r][sk]     = w0[r];
                *(b16x8*)&Bs[srow + 64*r][sk + 8] = w1[r];
            }
            __syncthreads();
            #pragma unroll
            for (int kc=0;kc<2;kc++){
                b16x8 a = *(const b16x8*)&As[wr16 + lr][kc*32 + lg*8];
                #pragma unroll
                for (int cb=0;cb<8;cb++){
                    b16x8 b = *(const b16x8*)&Bs[(ch+cb)*16 + lr][kc*32 + lg*8];
                    acc[cb] = __builtin_amdgcn_mfma_f32_16x16x32_bf16(a, b, acc[cb], 0,0,0);
                }
            }
        }
    }
    #pragma unroll
    for (int cb=0;cb<8;cb++){
        int col = (ch+cb)*16 + lr;
        float bias = Bias[col];
        #pragma unroll
        for (int i=0;i<4;i++){
            int row = mBase + wr16 + lg*4 + i;
            Out[(size_t)row*CC + col] = acc[cb][i] + bias;
        }
    }
}

// ---------------- conv weight: (O,I,3,3) -> bf16 [o][pos*512+i] -------------------------
__global__ void wtransb_k(const float* __restrict__ wsrc, short* __restrict__ wt){
    int o = blockIdx.x;
    int i = threadIdx.x;
    #pragma unroll
    for (int pos = 0; pos < 9; pos++)
        wt[(size_t)o*KCONV + pos*C2 + i] = f2b(wsrc[((size_t)o*C2 + i)*9 + pos]);
}

// ---------------- generic weight: (K,N) f32 -> (N,K) bf16 -------------------------------
__global__ void wtb_k(const float* __restrict__ src, short* __restrict__ dst, int K, int N){
    int n = blockIdx.x;
    for (int k = threadIdx.x; k < K; k += 256)
        dst[(size_t)n*K + k] = f2b(src[(size_t)k*N + n]);
}

// ---------------- f64 -> bf16 copy ------------------------------------------------------
__global__ void d2b_k(const double* __restrict__ src, short* __restrict__ dst){
    int i = blockIdx.x*256 + threadIdx.x;
    dst[i] = f2b((float)src[i]);
}

// ---------------- per-sample GroupNorm stats, CHUNK: grid (169, nb) ---------------------
__global__ __launch_bounds__(256) void gn_stats_k(const double* __restrict__ t2c,
    double* __restrict__ stats, int nOff){
    const double* p = t2c + (size_t)blockIdx.y*SAMP16;
    int i0 = blockIdx.x*4096 + threadIdx.x;
    double s = 0.0, q = 0.0;
    #pragma unroll
    for (int r = 0; r < 16; r++){
        double v = p[i0 + r*256];
        s += v; q += v*v;
    }
    #pragma unroll
    for (int off = 32; off; off >>= 1){
        s += __shfl_xor(s, off);
        q += __shfl_xor(q, off);
    }
    __shared__ double ls[4], lq[4];
    int wid = threadIdx.x >> 6;
    if ((threadIdx.x & 63) == 0){ ls[wid] = s; lq[wid] = q; }
    __syncthreads();
    if (threadIdx.x == 0){
        int n = nOff + blockIdx.y;
        atomicAdd(&stats[n*2+0], ls[0]+ls[1]+ls[2]+ls[3]);
        atomicAdd(&stats[n*2+1], lq[0]+lq[1]+lq[2]+lq[3]);
    }
}

// ---------------- mx(chunk) = GN(t2c)+x, f64 out; grid = nb*LL --------------------------
__global__ void merge_x_k(const double* __restrict__ t2c, const float* __restrict__ x,
    const float* __restrict__ g, const float* __restrict__ b,
    const double* __restrict__ stats, int nOff, double* __restrict__ mxn){
    int idx = blockIdx.x*256 + threadIdx.x;
    const double inv = 1.0/((double)LL*CC);
    int c = idx & (CC-1);
    int n = nOff + idx / (LL*CC);
    double mu = stats[2*n]*inv;
    double var = stats[2*n+1]*inv - mu*mu;
    double r = 1.0/sqrt(var + 1e-5);
    mxn[idx] = (t2c[idx]-mu)*r*(double)g[c] + (double)b[c] + (double)x[idx];
}

// ---------------- mc(chunk) = down(GN(t2c)) + center, f64 out; grid = nb*SS -------------
__global__ void merge_c_k(const double* __restrict__ t2c, const float* __restrict__ cen,
    const float* __restrict__ g, const float* __restrict__ b,
    const double* __restrict__ stats, int nOff, double* __restrict__ mcn){
    int idx = blockIdx.x*256 + threadIdx.x;
    int c = idx & 255;
    int ns = idx >> 8;
    int nl = ns / SS, s = ns % SS;
    int i = s / WC, j = s % WC;
    double fy = (i==WC-1) ? (double)(HH-1) : i*((double)(HH-1)/(HC-1));
    double fx = (j==WC-1) ? (double)(WW-1) : j*((double)(WW-1)/(WC-1));
    int y0 = (int)fy; int y1 = min(y0+1, HH-1);
    int x0 = (int)fx; int x1 = min(x0+1, WW-1);
    double dy = fy - y0, dx = fx - x0;
    const double* base = t2c + (size_t)nl*SAMP16 + c;
    double v00 = base[(size_t)(y0*WW + x0)*CC];
    double v01 = base[(size_t)(y0*WW + x1)*CC];
    double v10 = base[(size_t)(y1*WW + x0)*CC];
    double v11 = base[(size_t)(y1*WW + x1)*CC];
    double r0 = v00*(1.0-dy) + v10*dy;
    double r1 = v01*(1.0-dy) + v11*dy;
    double v = r0*(1.0-dx) + r1*dx;
    const double inv = 1.0/((double)LL*CC);
    int n = nOff + nl;
    double mu = stats[2*n]*inv;
    double var = stats[2*n+1]*inv - mu*mu;
    double r = 1.0/sqrt(var + 1e-5);
    mcn[idx] = (v-mu)*r*(double)g[c] + (double)b[c] + (double)cen[idx];
}

// ---------------- normalize cpt -> ctn (n*8+h, s, 32), f64 (full) -----------------------
__global__ __launch_bounds__(256) void cptn_k(const double* __restrict__ cp, double* __restrict__ ctn){
    int ns = blockIdx.x;
    int n = ns / SS, s = ns % SS;
    int hgrp = threadIdx.x >> 5, k = threadIdx.x & 31;
    double v = cp[(size_t)ns*C2 + hgrp*64 + k];
    double q = v*v;
    #pragma unroll
    for (int off = 16; off; off >>= 1) q += __shfl_xor(q, off, 32);
    double d = fmax(sqrt(q), 1e-12);
    ctn[((size_t)(n*FCn + hgrp)*SS + s)*SCn + k] = v/d;
}

// ---------------- sim via f64 MFMA on RAW dots + running argmax, in-kernel norms --------
// grid (43, 8, nz). xpc base = chunk/pyramid base; n index for ctn/cp/disp = nOff + nl.
__global__ __launch_bounds__(256) void sim3_k(
    const double* __restrict__ xpc,     // [nz][LL][256]
    const double* __restrict__ ctn,     // full [n*8+h][SS][32]
    const double* __restrict__ cp,      // full
    const float* __restrict__ alpha_p, const float* __restrict__ beta_p,
    int nOff, short* __restrict__ dispb)
{
    __shared__ double xs[32][65];
    __shared__ double cs[32][65];
    __shared__ double redn[4][64];
    const int t = threadIdx.x;
    const int lBase = blockIdx.x * 64;
    const int h = blockIdx.y;
    const int nl = blockIdx.z;
    const int n = nOff + nl;
    const int w  = t >> 6;
    const int wr = (w >> 1) * 32;
    const int wc = (w & 1) * 32;
    const int lane = t & 63;
    const int lr = lane & 15, lk = lane >> 4;
    const double alpha = (double)alpha_p[0], beta = (double)beta_p[0];
    const double sgn = (alpha >= 0.0) ? 1.0 : -1.0;

    dvec4 prm = {0.,0.,0.,0.}, prn = {0.,0.,0.,0.};
    prm = __builtin_amdgcn_mfma_f64_16x16x4f64((double)lr, 0.25, prm, 0,0,0);
    prn = __builtin_amdgcn_mfma_f64_16x16x4f64(0.25, (double)lr, prn, 0,0,0);
    int pm[4], pn[4];
    #pragma unroll
    for (int i=0;i<4;i++){ pm[i] = (int)prm[i]; pn[i] = (int)prn[i]; }

    const int lav = min(64, LL - lBase);
    #pragma unroll
    for (int r = 0; r < 8; r++){
        int idx = t + r*256;
        int li = idx >> 5, ki = idx & 31;
        double v = 0.0;
        if (li < lav) v = xpc[((size_t)nl*LL + lBase + li)*CC + h*SCn + ki];
        xs[ki][li] = v;
    }
    __syncthreads();
    // in-kernel row norms from the staged tile
    {
        int li = t & 63, q4 = t >> 6;
        double part = 0.0;
        #pragma unroll
        for (int ki = 0; ki < 8; ki++){
            double v = xs[q4*8 + ki][li];
            part += v*v;
        }
        redn[q4][li] = part;
    }
    __syncthreads();
    double myNrm = 1e-12;
    if (t < 64) myNrm = fmax(sqrt(redn[0][t]+redn[1][t]+redn[2][t]+redn[3][t]), 1e-12);

    double bz[2][2][4];
    int    bs[2][2][4];
    #pragma unroll
    for (int rf=0; rf<2; rf++)
        #pragma unroll
        for (int j=0; j<2; j++)
            #pragma unroll
            for (int i=0; i<4; i++){ bz[rf][j][i] = -1.0e300; bs[rf][j][i] = 0; }

    const double* cbase = ctn + ((size_t)(n*FCn + h))*SS*SCn;
    for (int sBase = 0; sBase < SS; sBase += 64){
        const int sav = min(64, SS - sBase);
        const double* cb = cbase + (size_t)sBase*SCn;
        __syncthreads();
        #pragma unroll
        for (int r = 0; r < 8; r++){
            int idx = t + r*256;
            int si = idx >> 5, ki = idx & 31;
            cs[ki][si] = (si < sav) ? cb[idx] : 0.0;
        }
        __syncthreads();
        dvec4 a00 = {0.,0.,0.,0.}, a01 = {0.,0.,0.,0.};
        dvec4 a10 = {0.,0.,0.,0.}, a11 = {0.,0.,0.,0.};
        #pragma unroll
        for (int ks = 0; ks < 8; ks++){
            double xa0 = xs[ks*4+lk][wr+lr];
            double xa1 = xs[ks*4+lk][wr+16+lr];
            double cb0 = cs[ks*4+lk][wc+lr];
            double cb1 = cs[ks*4+lk][wc+16+lr];
            a00 = __builtin_amdgcn_mfma_f64_16x16x4f64(xa0,cb0,a00,0,0,0);
            a01 = __builtin_amdgcn_mfma_f64_16x16x4f64(xa0,cb1,a01,0,0,0);
            a10 = __builtin_amdgcn_mfma_f64_16x16x4f64(xa1,cb0,a10,0,0,0);
            a11 = __builtin_amdgcn_mfma_f64_16x16x4f64(xa1,cb1,a11,0,0,0);
        }
        #pragma unroll
        for (int i=0;i<4;i++){
            int s0 = sBase + wc + pn[i];
            int s1 = s0 + 16;
            if (s0 < SS){
                double z = sgn*a00[i];
                if (z > bz[0][0][i]){ bz[0][0][i] = z; bs[0][0][i] = s0; }
                z = sgn*a10[i];
                if (z > bz[1][0][i]){ bz[1][0][i] = z; bs[1][0][i] = s0; }
            }
            if (s1 < SS){
                double z = sgn*a01[i];
                if (z > bz[0][1][i]){ bz[0][1][i] = z; bs[0][1][i] = s1; }
                z = sgn*a11[i];
                if (z > bz[1][1][i]){ bz[1][1][i] = z; bs[1][1][i] = s1; }
            }
        }
    }
    __syncthreads();
    double* redv = &xs[0][0];
    int*    redi = (int*)&cs[0][0];
    #pragma unroll
    for (int rf=0; rf<2; rf++){
        #pragma unroll
        for (int i=0;i<4;i++){
            double z0 = bz[rf][0][i]; int i0 = bs[rf][0][i];
            double z1 = bz[rf][1][i]; int i1 = bs[rf][1][i];
            bool take1 = (z1 > z0) || (z1 == z0 && i1 < i0);
            double z = take1 ? z1 : z0;
            int    s = take1 ? i1 : i0;
            int row = wr + rf*16 + pm[i];
            int cls = (w & 1)*16 + pn[i];
            redv[row*32 + cls] = z;
            redi[row*32 + cls] = s;
        }
    }
    __syncthreads();
    if (t < 64){
        double best = redv[t*32]; int bi = redi[t*32];
        #pragma unroll
        for (int c = 1; c < 32; c++){
            double v = redv[t*32 + c]; int ii = redi[t*32 + c];
            if (v > best || (v == best && ii < bi)){ best = v; bi = ii; }
        }
        int l = lBase + t;
        if (l < LL){
            double zb = alpha*((sgn*best)/myNrm) + beta;
            double val;
            if (zb >= 0.0) val = 1.0/(1.0 + exp(-zb));
            else { double e = exp(zb); val = e/(1.0+e); }
            const double* cv = cp + ((size_t)(n*SS + bi))*C2 + h*64 + 32;
            short* dr = dispb + ((size_t)(n*LL + l))*CC + h*SCn;
            #pragma unroll
            for (int k=0;k<32;k++) dr[k] = f2b((float)(val*cv[k]));
        }
    }
}

// ---------------- row LayerNorm f32 -> bf16 (row = 256) ---------------------------------
__global__ __launch_bounds__(256) void ln_bf_k(const float* __restrict__ y,
    const float* __restrict__ g, const float* __restrict__ b, short* __restrict__ ob){
    int row = blockIdx.x*4 + (threadIdx.x >> 6);
    int lane = threadIdx.x & 63;
    const float* rp = y + (size_t)row*CC;
    float4 v = *(const float4*)(rp + lane*4);
    float s = v.x+v.y+v.z+v.w;
    float q = v.x*v.x+v.y*v.y+v.z*v.z+v.w*v.w;
    #pragma unroll
    for (int off = 32; off; off >>= 1){ s += __shfl_xor(s, off); q += __shfl_xor(q, off); }
    float mu = s*(1.0f/CC);
    float var = q*(1.0f/CC) - mu*mu;
    float r = rsqrtf(var + 1e-5f);
    int c = lane*4;
    float4 gv = *(const float4*)(g+c);
    float4 bv = *(const float4*)(b+c);
    short* op = ob + (size_t)row*CC + c;
    op[0] = f2b((v.x-mu)*r*gv.x+bv.x);
    op[1] = f2b((v.y-mu)*r*gv.y+bv.y);
    op[2] = f2b((v.z-mu)*r*gv.z+bv.z);
    op[3] = f2b((v.w-mu)*r*gv.w+bv.w);
}

// ---------------- final: out = LN(out)*g+b + res(f64) -----------------------------------
__global__ __launch_bounds__(256) void final_k(float* __restrict__ y, const double* __restrict__ res,
    const float* __restrict__ g, const float* __restrict__ b){
    int row = blockIdx.x*4 + (threadIdx.x >> 6);
    int lane = threadIdx.x & 63;
    float* rp = y + (size_t)row*CC;
    const double* xp = res + (size_t)row*CC;
    float4 v = *(const float4*)(rp + lane*4);
    float s = v.x+v.y+v.z+v.w;
    float q = v.x*v.x+v.y*v.y+v.z*v.z+v.w*v.w;
    #pragma unroll
    for (int off = 32; off; off >>= 1){ s += __shfl_xor(s, off); q += __shfl_xor(q, off); }
    float mu = s*(1.0f/CC);
    float var = q*(1.0f/CC) - mu*mu;
    float r = rsqrtf(var + 1e-5f);
    int c = lane*4;
    float4 gv = *(const float4*)(g+c);
    float4 bv = *(const float4*)(b+c);
    float4 o;
    o.x = (v.x-mu)*r*gv.x+bv.x + (float)xp[c+0];
    o.y = (v.y-mu)*r*gv.y+bv.y + (float)xp[c+1];
    o.z = (v.z-mu)*r*gv.z+bv.z + (float)xp[c+2];
    o.w = (v.w-mu)*r*gv.w+bv.w + (float)xp[c+3];
    *(float4*)(rp+c) = o;
}

extern "C" void kernel_launch(void* const* d_in, const int* in_sizes, int n_in,
                              void* d_out, int out_size, void* d_ws, size_t ws_size,
                              hipStream_t stream)
{
    const float* x16[2] = {(const float*)d_in[0], (const float*)d_in[1]};
    const float* x32[2] = {(const float*)d_in[2], (const float*)d_in[3]};
    const float* mb_l0_w = (const float*)d_in[6];
    const float* mb_l0_b = (const float*)d_in[7];
    const float* mb_l1_w = (const float*)d_in[8];
    const float* mb_l1_b = (const float*)d_in[9];
    const float* mb_gn_g = (const float*)d_in[10];
    const float* mb_gn_b = (const float*)d_in[11];
    const float* gc_p0_w = (const float*)d_in[12];
    const float* gc_p0_b = (const float*)d_in[13];
    const float* gc_p1_w = (const float*)d_in[14];
    const float* gc_p1_b = (const float*)d_in[15];
    const float* gc_m_w  = (const float*)d_in[16];
    const float* gc_m_b  = (const float*)d_in[17];
    const float* gc_alpha= (const float*)d_in[18];
    const float* gc_beta = (const float*)d_in[19];
    const float* gb_n0_g = (const float*)d_in[20];
    const float* gb_n0_b = (const float*)d_in[21];
    const float* gb_lin_w= (const float*)d_in[22];
    const float* gb_lin_b= (const float*)d_in[23];
    const float* gb_conv_w=(const float*)d_in[24];
    const float* gb_conv_b=(const float*)d_in[25];
    const float* gb_n1_g = (const float*)d_in[26];
    const float* gb_n1_b = (const float*)d_in[27];

    // ---------------- workspace layout (bytes) ----------------
    const size_t F8  = (size_t)M16*CC*8;      // 44,302,336
    const size_t G8  = (size_t)M32*CC*8;      // 11,075,584
    const size_t WT4 = (size_t)KCONV*CC*4;    //  4,718,592

    char* base = (char*)d_ws;
    double* mx[2] = { (double*)base, (double*)(base + F8) };
    double* mc[2] = { (double*)(base + 2*F8), (double*)(base + 2*F8 + G8) };
    char*   pWT   = base + 2*F8 + 2*G8;
    short*  WTb   = (short*)pWT;                       // 2,359,296
    short*  WLb   = (short*)(pWT + 2359296);           //   524,288
    short*  WMb   = (short*)(pWT + 2883584);           //   131,072
    double* stats = (double*)(pWT + WT4);
    char*   E     = pWT + WT4 + 256;
    const size_t base_need = 2*F8 + 2*G8 + WT4 + 256;

    // chunk size nb for the merge phase; combined gc_p0 if xpc2 fits.
    const size_t T2  = (size_t)LL*CC*8;   // 5,537,792 per sample (f64, 256-wide)
    const size_t T1  = (size_t)LL*C2*8;   // 11,075,584 per sample (f64, 512-wide)
    const size_t TC  = (size_t)SS*C2*8;   //  2,768,896 per sample (cw, f64 512-wide)
    int nb = 1;
    {
        const int cands[4] = {8,4,2,1};
        for (int ci = 0; ci < 4; ci++){
            int c = cands[ci];
            size_t merge_r  = (size_t)c*(T2 + T1 + TC);
            size_t global_r = 55377920ull + (size_t)c*T2;   // cp+ctn+dispb+mxb + xpc(chunk)
            size_t r = merge_r > global_r ? merge_r : global_r;
            if (base_need + r <= ws_size){ nb = c; break; }
            if (c == 1) return;
        }
    }
    const size_t XPC2 = 2ull*NB*T2;                         // 88,604,672
    const bool combined = (base_need + 55377920ull + XPC2 <= ws_size);

    // merge-phase scratch (chunk of nb samples)
    double* t2c = (double*)E;
    double* t1c = (double*)(E + nb*T2);
    double* cwb = (double*)(E + nb*(T2 + T1));
    // global-phase scratch
    double* cp    = (double*)E;                              // 22,151,168
    double* ctn   = (double*)(E + 22151168);                 // 11,075,584
    double* xpc   = (double*)(E + 33226752);                 // combined? 2*NB*T2 : nb*T2
    const size_t xsz = combined ? XPC2 : (size_t)nb*T2;
    short*  dispb = (short*) (E + 33226752 + xsz);           // 11,075,584
    short*  mxb   = (short*) (E + 33226752 + xsz + 11075584);// 11,075,584
    float*  Dbuf  = (float*) E;                              // over cp (after sims)
    short*  Dbufb = (short*) (E + 22151168);                 // over ctn (after ln)
    short*  Bbufb = (short*) E;                              // over Dbuf (after gb_lin)

    wtransb_k<<<CC, C2, 0, stream>>>(gb_conv_w, WTb);
    wtb_k<<<C2, 256, 0, stream>>>(gb_lin_w, WLb, C2, C2);
    wtb_k<<<CC, 256, 0, stream>>>(gc_m_w, WMb, CC, CC);

    const int Mc = nb*LL;
    const int Ms = nb*SS;
    const int mTiles  = (Mc + 127) / 128;
    const int sTiles  = (Ms + 127) / 128;

    // -------- merge blocks (f64 MFMA, chunked; mb_l0 factorized) --------
    for (int i = 0; i < 2; i++){
        hipMemsetAsync(stats, 0, 16*sizeof(double), stream);
        for (int ch = 0; ch < NB; ch += nb){
            const float* x16c = x16[i] + (size_t)ch*SAMP16;
            const float* x32c = x32[i] + (size_t)ch*SAMP32;
            gemm_d64<float,double,false,false,false><<<dim3(8, sTiles), 256, 0, stream>>>(
                x32c, mb_l0_w + (size_t)CC*C2, mb_l0_b, nullptr, cwb, Ms, CC, C2);
            gemm_d64<float,double,true,true,true><<<dim3(8, mTiles), 256, 0, stream>>>(
                x16c, mb_l0_w, mb_l0_b, cwb, t1c, Mc, CC, C2);
            gemm_d64<double,double,false,true,false><<<dim3(4, mTiles), 256, 0, stream>>>(
                t1c, mb_l1_w, mb_l1_b, nullptr, t2c, Mc, C2, CC);
            gn_stats_k<<<dim3(169, nb), 256, 0, stream>>>(t2c, stats, ch);
            merge_x_k<<<nb*LL, 256, 0, stream>>>(t2c, x16c,
                mb_gn_g, mb_gn_b, stats, ch, mx[i] + (size_t)ch*SAMP16);
            merge_c_k<<<nb*SS, 256, 0, stream>>>(t2c, x32c,
                mb_gn_g, mb_gn_b, stats, ch, mc[i] + (size_t)ch*SAMP32);
        }
    }

    // -------- global blocks (f64 pre-sim, bf16-MFMA post-sim) --------
    float* outp[2] = { (float*)d_out, (float*)d_out + (size_t)M16*CC };
    if (combined){
        // one big gc_p0 over both pyramids (mx[0]||mx[1] contiguous)
        gemm_d64<double,double,false,true,false><<<dim3(4, (2*M16+127)/128), 256, 0, stream>>>(
            mx[0], gc_p0_w, gc_p0_b, nullptr, xpc, 2*M16, CC, CC);
    }
    for (int i = 0; i < 2; i++){
        const double* xi64 = mx[i];
        const double* ci64 = mc[1-i];
        gemm_d64<double,double,false,true,false><<<dim3(8, (M32+127)/128), 256, 0, stream>>>(
            ci64, gc_p1_w, gc_p1_b, nullptr, cp, M32, CC, C2);
        cptn_k<<<M32, 256, 0, stream>>>(cp, ctn);
        if (combined){
            sim3_k<<<dim3((LL+63)/64, FCn, NB), 256, 0, stream>>>(
                xpc + (size_t)i*NB*SAMP16, ctn, cp, gc_alpha, gc_beta, 0, dispb);
        } else {
            for (int ch = 0; ch < NB; ch += nb){
                gemm_d64<double,double,false,true,false><<<dim3(4, mTiles), 256, 0, stream>>>(
                    xi64 + (size_t)ch*SAMP16, gc_p0_w, gc_p0_b, nullptr, xpc, Mc, CC, CC);
                sim3_k<<<dim3((LL+63)/64, FCn, nb), 256, 0, stream>>>(
                    xpc, ctn, cp, gc_alpha, gc_beta, ch, dispb);
            }
        }
        d2b_k<<<(M16*CC)/256, 256, 0, stream>>>(xi64, mxb);
        gemm_bf<false,false,false><<<dim3(4, 338), 256, 0, stream>>>(
            dispb, (const short*)nullptr, CC, WMb, gc_m_b, Dbuf, M16, CC, CC);
        ln_bf_k<<<M16/4, 256, 0, stream>>>(Dbuf, gb_n0_g, gb_n0_b, Dbufb);
        gemm_bf<true,true,true><<<dim3(8, 338), 256, 0, stream>>>(
            mxb, Dbufb, CC, WLb, gb_lin_b, Bbufb, M16, C2, C2);
        conv_bf2<<<M16/32, 256, 0, stream>>>(Bbufb, WTb, gb_conv_b, outp[i]);
        final_k<<<M16/4, 256, 0, stream>>>(outp[i], xi64, gb_n1_g, gb_n1_b);
    }
}

// Round 14
// 2381.412 us; speedup vs baseline: 1.0572x; 1.0572x over previous
//
#include <hip/hip_runtime.h>
#include <math.h>

#define NB 8
#define HH 52
#define WW 52
#define LL 2704
#define CC 256
#define HC 26
#define WC 26
#define SS 676
#define C2 512
#define FCn 8
#define SCn 32
#define M16 (NB*LL)     // 21632
#define M32 (NB*SS)     // 5408
#define KCONV (9*C2)    // 4608
#define SAMP16 ((size_t)LL*CC)
#define SAMP32 ((size_t)SS*CC)

typedef double dvec4 __attribute__((ext_vector_type(4)));
typedef float  f32x4 __attribute__((ext_vector_type(4)));
typedef short  b16x8 __attribute__((ext_vector_type(8)));

__device__ __forceinline__ float  gelu_ct(float x){ return 0.5f*x*(1.0f + erff(x*0.70710678118654752f)); }
__device__ __forceinline__ double gelu_ct(double x){ return 0.5*x*(1.0 + erf(x*0.70710678118654752440)); }

__device__ __forceinline__ short f2b(float x){
    union { float f; unsigned u; } v; v.f = x;
    unsigned r = v.u + 0x7fffu + ((v.u >> 16) & 1u);
    return (short)(r >> 16);
}

// ================= f64 MFMA GEMM v2: BK=32, reg-prefetch pipeline =======================
template<typename TA0, typename TA1, typename TO, bool GELU, bool CAT>
__global__ __launch_bounds__(256) void gemm_d64(
    const TA0* __restrict__ A0, const TA1* __restrict__ A1, int K0,
    const float* __restrict__ W, const float* __restrict__ Bias,
    TO* __restrict__ Out, int M, int K, int N)
{
    __shared__ double As[32][65];
    __shared__ double Bs[32][65];
    const int t = threadIdx.x;
    const int mBase = blockIdx.y * 64;
    const int nBase = blockIdx.x * 64;
    const int arow = t >> 2;          // 0..63
    const int kofA = (t & 3) << 3;    // 0,8,16,24
    const int kb   = (t >> 4) << 1;   // 0,2,..,30
    const int nof  = (t & 15) << 2;   // 0..60
    const int w  = t >> 6;
    const int wr = (w >> 1) * 32;
    const int wc = (w & 1) * 32;
    const int lane = t & 63;
    const int lr = lane & 15, lk = lane >> 4;

    // layout probe (exact integer f64 arithmetic)
    dvec4 prm = {0.,0.,0.,0.}, prn = {0.,0.,0.,0.};
    prm = __builtin_amdgcn_mfma_f64_16x16x4f64((double)lr, 0.25, prm, 0,0,0);
    prn = __builtin_amdgcn_mfma_f64_16x16x4f64(0.25, (double)lr, prn, 0,0,0);
    int pm[4], pn[4];
    #pragma unroll
    for (int i=0;i<4;i++){ pm[i] = (int)prm[i]; pn[i] = (int)prn[i]; }

    dvec4 acc00 = {0.,0.,0.,0.}, acc01 = {0.,0.,0.,0.};
    dvec4 acc10 = {0.,0.,0.,0.}, acc11 = {0.,0.,0.,0.};
    const int am = mBase + arow;

    double aReg[8], bReg[8];
    auto loadA = [&](int k0){
        #pragma unroll
        for (int j=0;j<8;j++){
            int k = k0 + kofA + j;
            double v = 0.0;
            if (am < M){
                if (!CAT || k < K0) v = (double)A0[(size_t)am*K0 + k];
                else                v = (double)A1[(size_t)am*(K-K0) + (k-K0)];
            }
            aReg[j] = v;
        }
    };
    auto loadB = [&](int k0){
        #pragma unroll
        for (int r=0;r<2;r++)
            #pragma unroll
            for (int j=0;j<4;j++)
                bReg[r*4+j] = (double)W[(size_t)(k0+kb+r)*N + nBase + nof + j];
    };
    loadA(0); loadB(0);
    for (int k0 = 0; k0 < K; k0 += 32){
        __syncthreads();
        #pragma unroll
        for (int j=0;j<8;j++) As[kofA+j][arow] = aReg[j];
        #pragma unroll
        for (int r=0;r<2;r++)
            #pragma unroll
            for (int j=0;j<4;j++) Bs[kb+r][nof+j] = bReg[r*4+j];
        __syncthreads();
        if (k0 + 32 < K){ loadA(k0+32); loadB(k0+32); }
        #pragma unroll
        for (int ks = 0; ks < 8; ks++){
            double a0 = As[ks*4+lk][wr+lr];
            double a1 = As[ks*4+lk][wr+16+lr];
            double b0 = Bs[ks*4+lk][wc+lr];
            double b1 = Bs[ks*4+lk][wc+16+lr];
            acc00 = __builtin_amdgcn_mfma_f64_16x16x4f64(a0,b0,acc00,0,0,0);
            acc01 = __builtin_amdgcn_mfma_f64_16x16x4f64(a0,b1,acc01,0,0,0);
            acc10 = __builtin_amdgcn_mfma_f64_16x16x4f64(a1,b0,acc10,0,0,0);
            acc11 = __builtin_amdgcn_mfma_f64_16x16x4f64(a1,b1,acc11,0,0,0);
        }
    }
    #pragma unroll
    for (int i=0;i<4;i++){
        const int gm0 = mBase + wr + pm[i];
        const int gm1 = gm0 + 16;
        const int gn0 = nBase + wc + pn[i];
        const int gn1 = gn0 + 16;
        const double bias0 = (double)Bias[gn0];
        const double bias1 = (double)Bias[gn1];
        if (gm0 < M){
            double v0 = acc00[i] + bias0; if (GELU) v0 = gelu_ct(v0);
            double v1 = acc01[i] + bias1; if (GELU) v1 = gelu_ct(v1);
            Out[(size_t)gm0*N + gn0] = (TO)v0;
            Out[(size_t)gm0*N + gn1] = (TO)v1;
        }
        if (gm1 < M){
            double v0 = acc10[i] + bias0; if (GELU) v0 = gelu_ct(v0);
            double v1 = acc11[i] + bias1; if (GELU) v1 = gelu_ct(v1);
            Out[(size_t)gm1*N + gn0] = (TO)v0;
            Out[(size_t)gm1*N + gn1] = (TO)v1;
        }
    }
}

// ================= bf16 MFMA GEMM, bf16 A-inputs (post-argmax path) =====================
template<bool GELU, bool CAT, bool OUT_BF>
__global__ __launch_bounds__(256) void gemm_bf(
    const short* __restrict__ A0, const short* __restrict__ A1, int K0,
    const short* __restrict__ Wb, const float* __restrict__ Bias,
    void* __restrict__ OutV, int M, int K, int N)
{
    __shared__ short As[64][72];
    __shared__ short Bs[64][72];
    const int t = threadIdx.x;
    const int mBase = blockIdx.y*64, nBase = blockIdx.x*64;
    const int lane = t & 63, lr = lane & 15, lg = lane >> 4;
    const int wr = (t >> 6) * 16;
    const int srow = t >> 2;
    const int sk   = (t & 3) * 16;
    const int am = mBase + srow;
    const int bo = nBase + srow;
    f32x4 acc[4] = {{0,0,0,0},{0,0,0,0},{0,0,0,0},{0,0,0,0}};

    for (int c0 = 0; c0 < K; c0 += 64){
        const int kk = c0 + sk;
        const short* ap;
        if (!CAT || kk < K0) ap = A0 + (size_t)am*K0 + kk;
        else                 ap = A1 + (size_t)am*(K-K0) + (kk - K0);
        b16x8 a0 = *(const b16x8*)ap;
        b16x8 a1 = *(const b16x8*)(ap + 8);
        b16x8 bv0 = *(const b16x8*)&Wb[(size_t)bo*K + kk];
        b16x8 bv1 = *(const b16x8*)&Wb[(size_t)bo*K + kk + 8];
        __syncthreads();
        *(b16x8*)&As[srow][sk]     = a0;
        *(b16x8*)&As[srow][sk + 8] = a1;
        *(b16x8*)&Bs[srow][sk]     = bv0;
        *(b16x8*)&Bs[srow][sk + 8] = bv1;
        __syncthreads();
        #pragma unroll
        for (int kc=0;kc<2;kc++){
            b16x8 a = *(const b16x8*)&As[wr + lr][kc*32 + lg*8];
            #pragma unroll
            for (int cb=0;cb<4;cb++){
                b16x8 b = *(const b16x8*)&Bs[cb*16 + lr][kc*32 + lg*8];
                acc[cb] = __builtin_amdgcn_mfma_f32_16x16x32_bf16(a, b, acc[cb], 0,0,0);
            }
        }
    }
    #pragma unroll
    for (int cb=0;cb<4;cb++){
        int col = nBase + cb*16 + lr;
        float bias = Bias[col];
        #pragma unroll
        for (int i=0;i<4;i++){
            int row = mBase + wr + lg*4 + i;
            float v = acc[cb][i] + bias;
            if (GELU) v = gelu_ct(v);
            if (OUT_BF) ((short*)OutV)[(size_t)row*N + col] = f2b(v);
            else        ((float*)OutV)[(size_t)row*N + col] = v;
        }
    }
}

// ================= 3x3 conv, bf16 MFMA, M-tile 32 x N=256; grid = 676 ===================
__global__ __launch_bounds__(256) void conv_bf2(const short* __restrict__ Xb,
    const short* __restrict__ WTb, const float* __restrict__ Bias, float* __restrict__ Out)
{
    __shared__ short As[32][72];
    __shared__ short Bs[256][72];
    const int t = threadIdx.x;
    const int mBase = blockIdx.x*32;
    const int lane = t & 63, lr = lane & 15, lg = lane >> 4;
    const int w = t >> 6;
    const int wr16 = (w & 1) * 16;     // row half
    const int ch   = (w >> 1) * 8;     // col-frag offset (0 or 8)
    const int arow = t >> 3;           // 0..31 (A staging)
    const int ska  = (t & 7) * 8;      // 0..56
    const int srow = t >> 2;           // 0..63 (B staging)
    const int sk   = (t & 3) * 16;
    const int am = mBase + arow;
    const int an = am / LL; const int ahw = am % LL;
    const int ah = ahw / WW; const int aw = ahw % WW;
    f32x4 acc[8];
    #pragma unroll
    for (int i=0;i<8;i++) acc[i] = (f32x4){0.f,0.f,0.f,0.f};
    const b16x8 z = {0,0,0,0,0,0,0,0};

    for (int pos = 0; pos < 9; pos++){
        const int dh = pos/3 - 1, dw = pos%3 - 1;
        const int h2 = ah + dh, w2 = aw + dw;
        const bool ok = (h2 >= 0 && h2 < HH && w2 >= 0 && w2 < WW);
        const short* xrow = Xb + ((size_t)(an*LL + h2*WW + w2))*C2;
        for (int c0 = 0; c0 < C2; c0 += 64){
            b16x8 a0 = ok ? *(const b16x8*)&xrow[c0 + ska] : z;
            b16x8 w0[4], w1[4];
            #pragma unroll
            for (int r=0;r<4;r++){
                const short* wp = WTb + (size_t)(srow + 64*r)*KCONV + pos*C2 + c0 + sk;
                w0[r] = *(const b16x8*)wp;
                w1[r] = *(const b16x8*)(wp + 8);
            }
            __syncthreads();
            *(b16x8*)&As[arow][ska] = a0;
            #pragma unroll
            for (int r=0;r<4;r++){
                *(b16x8*)&Bs[srow + 64*r][sk]     = w0[r];
                *(b16x8*)&Bs[srow + 64*r][sk + 8] = w1[r];
            }
            __syncthreads();
            #pragma unroll
            for (int kc=0;kc<2;kc++){
                b16x8 a = *(const b16x8*)&As[wr16 + lr][kc*32 + lg*8];
                #pragma unroll
                for (int cb=0;cb<8;cb++){
                    b16x8 b = *(const b16x8*)&Bs[(ch+cb)*16 + lr][kc*32 + lg*8];
                    acc[cb] = __builtin_amdgcn_mfma_f32_16x16x32_bf16(a, b, acc[cb], 0,0,0);
                }
            }
        }
    }
    #pragma unroll
    for (int cb=0;cb<8;cb++){
        int col = (ch+cb)*16 + lr;
        float bias = Bias[col];
        #pragma unroll
        for (int i=0;i<4;i++){
            int row = mBase + wr16 + lg*4 + i;
            Out[(size_t)row*CC + col] = acc[cb][i] + bias;
        }
    }
}

// ---------------- conv weight: (O,I,3,3) -> bf16 [o][pos*512+i] -------------------------
__global__ void wtransb_k(const float* __restrict__ wsrc, short* __restrict__ wt){
    int o = blockIdx.x;
    int i = threadIdx.x;
    #pragma unroll
    for (int pos = 0; pos < 9; pos++)
        wt[(size_t)o*KCONV + pos*C2 + i] = f2b(wsrc[((size_t)o*C2 + i)*9 + pos]);
}

// ---------------- generic weight: (K,N) f32 -> (N,K) bf16 -------------------------------
__global__ void wtb_k(const float* __restrict__ src, short* __restrict__ dst, int K, int N){
    int n = blockIdx.x;
    for (int k = threadIdx.x; k < K; k += 256)
        dst[(size_t)n*K + k] = f2b(src[(size_t)k*N + n]);
}

// ---------------- f64 -> bf16 copy ------------------------------------------------------
__global__ void d2b_k(const double* __restrict__ src, short* __restrict__ dst){
    int i = blockIdx.x*256 + threadIdx.x;
    dst[i] = f2b((float)src[i]);
}

// ---------------- bilinear upsample 26x26 -> 52x52, CHUNK of samples, f64 out -----------
__global__ void ups_k(const float* __restrict__ cen, double* __restrict__ up){
    int idx = blockIdx.x*256 + threadIdx.x;
    int c = idx & 255;
    int gl = idx >> 8;
    int n = gl / LL, l = gl % LL;
    int h = l / WW, w = l % WW;
    double fy = (h==HH-1) ? (double)(HC-1) : h*((double)(HC-1)/(HH-1));
    double fx = (w==WW-1) ? (double)(WC-1) : w*((double)(WC-1)/(WW-1));
    int y0 = (int)fy; int y1 = min(y0+1, HC-1);
    int x0 = (int)fx; int x1 = min(x0+1, WC-1);
    double dy = fy - y0, dx = fx - x0;
    const float* base = cen + (size_t)n*SAMP32 + c;
    double v00 = (double)base[(size_t)(y0*WC + x0)*CC];
    double v01 = (double)base[(size_t)(y0*WC + x1)*CC];
    double v10 = (double)base[(size_t)(y1*WC + x0)*CC];
    double v11 = (double)base[(size_t)(y1*WC + x1)*CC];
    double r0 = v00*(1.0-dy) + v10*dy;
    double r1 = v01*(1.0-dy) + v11*dy;
    up[idx] = r0*(1.0-dx) + r1*dx;
}

// ---------------- per-sample GroupNorm stats, CHUNK: grid (169, nb) ---------------------
__global__ __launch_bounds__(256) void gn_stats_k(const double* __restrict__ t2c,
    double* __restrict__ stats, int nOff){
    const double* p = t2c + (size_t)blockIdx.y*SAMP16;
    int i0 = blockIdx.x*4096 + threadIdx.x;
    double s = 0.0, q = 0.0;
    #pragma unroll
    for (int r = 0; r < 16; r++){
        double v = p[i0 + r*256];
        s += v; q += v*v;
    }
    #pragma unroll
    for (int off = 32; off; off >>= 1){
        s += __shfl_xor(s, off);
        q += __shfl_xor(q, off);
    }
    __shared__ double ls[4], lq[4];
    int wid = threadIdx.x >> 6;
    if ((threadIdx.x & 63) == 0){ ls[wid] = s; lq[wid] = q; }
    __syncthreads();
    if (threadIdx.x == 0){
        int n = nOff + blockIdx.y;
        atomicAdd(&stats[n*2+0], ls[0]+ls[1]+ls[2]+ls[3]);
        atomicAdd(&stats[n*2+1], lq[0]+lq[1]+lq[2]+lq[3]);
    }
}

// ---------------- mx(chunk) = GN(t2c)+x, f64 out; grid = nb*LL --------------------------
__global__ void merge_x_k(const double* __restrict__ t2c, const float* __restrict__ x,
    const float* __restrict__ g, const float* __restrict__ b,
    const double* __restrict__ stats, int nOff, double* __restrict__ mxn){
    int idx = blockIdx.x*256 + threadIdx.x;
    const double inv = 1.0/((double)LL*CC);
    int c = idx & (CC-1);
    int n = nOff + idx / (LL*CC);
    double mu = stats[2*n]*inv;
    double var = stats[2*n+1]*inv - mu*mu;
    double r = 1.0/sqrt(var + 1e-5);
    mxn[idx] = (t2c[idx]-mu)*r*(double)g[c] + (double)b[c] + (double)x[idx];
}

// ---------------- mc(chunk) = down(GN(t2c)) + center, f64 out; grid = nb*SS -------------
__global__ void merge_c_k(const double* __restrict__ t2c, const float* __restrict__ cen,
    const float* __restrict__ g, const float* __restrict__ b,
    const double* __restrict__ stats, int nOff, double* __restrict__ mcn){
    int idx = blockIdx.x*256 + threadIdx.x;
    int c = idx & 255;
    int ns = idx >> 8;
    int nl = ns / SS, s = ns % SS;
    int i = s / WC, j = s % WC;
    double fy = (i==WC-1) ? (double)(HH-1) : i*((double)(HH-1)/(HC-1));
    double fx = (j==WC-1) ? (double)(WW-1) : j*((double)(WW-1)/(WC-1));
    int y0 = (int)fy; int y1 = min(y0+1, HH-1);
    int x0 = (int)fx; int x1 = min(x0+1, WW-1);
    double dy = fy - y0, dx = fx - x0;
    const double* base = t2c + (size_t)nl*SAMP16 + c;
    double v00 = base[(size_t)(y0*WW + x0)*CC];
    double v01 = base[(size_t)(y0*WW + x1)*CC];
    double v10 = base[(size_t)(y1*WW + x0)*CC];
    double v11 = base[(size_t)(y1*WW + x1)*CC];
    double r0 = v00*(1.0-dy) + v10*dy;
    double r1 = v01*(1.0-dy) + v11*dy;
    double v = r0*(1.0-dx) + r1*dx;
    const double inv = 1.0/((double)LL*CC);
    int n = nOff + nl;
    double mu = stats[2*n]*inv;
    double var = stats[2*n+1]*inv - mu*mu;
    double r = 1.0/sqrt(var + 1e-5);
    mcn[idx] = (v-mu)*r*(double)g[c] + (double)b[c] + (double)cen[idx];
}

// ---------------- normalize cpt -> ctn (n*8+h, s, 32), f64 (full) -----------------------
__global__ __launch_bounds__(256) void cptn_k(const double* __restrict__ cp, double* __restrict__ ctn){
    int ns = blockIdx.x;
    int n = ns / SS, s = ns % SS;
    int hgrp = threadIdx.x >> 5, k = threadIdx.x & 31;
    double v = cp[(size_t)ns*C2 + hgrp*64 + k];
    double q = v*v;
    #pragma unroll
    for (int off = 16; off; off >>= 1) q += __shfl_xor(q, off, 32);
    double d = fmax(sqrt(q), 1e-12);
    ctn[((size_t)(n*FCn + hgrp)*SS + s)*SCn + k] = v/d;
}

// ---------------- per-(row,head) norms of xpc, CHUNK; grid (nb*338, 8) ------------------
__global__ __launch_bounds__(256) void norm_k(const double* __restrict__ xpc, double* __restrict__ norms){
    int t = threadIdx.x;
    int g = t >> 5, k = t & 31;
    int gl = blockIdx.x*8 + g;
    int nl = gl / LL, l = gl % LL;
    int h = blockIdx.y;
    double v = xpc[(size_t)gl*CC + h*SCn + k];
    double q = v*v;
    #pragma unroll
    for (int off = 16; off; off >>= 1) q += __shfl_xor(q, off, 32);
    if (k == 0) norms[((size_t)nl*FCn + h)*LL + l] = fmax(sqrt(q), 1e-12);
}

// ---------------- sim via f64 MFMA on RAW dots + running argmax, CHUNK ------------------
// grid (43, 8, nb). A = xpc (un-normalized); winner value uses norms table.
__global__ __launch_bounds__(256) void sim3_k(
    const double* __restrict__ xpc,     // [nb][LL][256]
    const double* __restrict__ norms,   // [nb][8][LL]
    const double* __restrict__ ctn,     // full [n*8+h][SS][32]
    const double* __restrict__ cp,      // full
    const float* __restrict__ alpha_p, const float* __restrict__ beta_p,
    int nOff, short* __restrict__ dispb)
{
    __shared__ double xs[32][65];
    __shared__ double cs[32][65];
    const int t = threadIdx.x;
    const int lBase = blockIdx.x * 64;
    const int h = blockIdx.y;
    const int nl = blockIdx.z;
    const int n = nOff + nl;
    const int w  = t >> 6;
    const int wr = (w >> 1) * 32;
    const int wc = (w & 1) * 32;
    const int lane = t & 63;
    const int lr = lane & 15, lk = lane >> 4;
    const double alpha = (double)alpha_p[0], beta = (double)beta_p[0];
    const double sgn = (alpha >= 0.0) ? 1.0 : -1.0;

    dvec4 prm = {0.,0.,0.,0.}, prn = {0.,0.,0.,0.};
    prm = __builtin_amdgcn_mfma_f64_16x16x4f64((double)lr, 0.25, prm, 0,0,0);
    prn = __builtin_amdgcn_mfma_f64_16x16x4f64(0.25, (double)lr, prn, 0,0,0);
    int pm[4], pn[4];
    #pragma unroll
    for (int i=0;i<4;i++){ pm[i] = (int)prm[i]; pn[i] = (int)prn[i]; }

    const int lav = min(64, LL - lBase);
    #pragma unroll
    for (int r = 0; r < 8; r++){
        int idx = t + r*256;
        int li = idx >> 5, ki = idx & 31;
        double v = 0.0;
        if (li < lav) v = xpc[((size_t)nl*LL + lBase + li)*CC + h*SCn + ki];
        xs[ki][li] = v;
    }

    double bz[2][2][4];
    int    bs[2][2][4];
    #pragma unroll
    for (int rf=0; rf<2; rf++)
        #pragma unroll
        for (int j=0; j<2; j++)
            #pragma unroll
            for (int i=0; i<4; i++){ bz[rf][j][i] = -1.0e300; bs[rf][j][i] = 0; }

    const double* cbase = ctn + ((size_t)(n*FCn + h))*SS*SCn;
    for (int sBase = 0; sBase < SS; sBase += 64){
        const int sav = min(64, SS - sBase);
        const double* cb = cbase + (size_t)sBase*SCn;
        __syncthreads();
        #pragma unroll
        for (int r = 0; r < 8; r++){
            int idx = t + r*256;
            int si = idx >> 5, ki = idx & 31;
            cs[ki][si] = (si < sav) ? cb[idx] : 0.0;
        }
        __syncthreads();
        dvec4 a00 = {0.,0.,0.,0.}, a01 = {0.,0.,0.,0.};
        dvec4 a10 = {0.,0.,0.,0.}, a11 = {0.,0.,0.,0.};
        #pragma unroll
        for (int ks = 0; ks < 8; ks++){
            double xa0 = xs[ks*4+lk][wr+lr];
            double xa1 = xs[ks*4+lk][wr+16+lr];
            double cb0 = cs[ks*4+lk][wc+lr];
            double cb1 = cs[ks*4+lk][wc+16+lr];
            a00 = __builtin_amdgcn_mfma_f64_16x16x4f64(xa0,cb0,a00,0,0,0);
            a01 = __builtin_amdgcn_mfma_f64_16x16x4f64(xa0,cb1,a01,0,0,0);
            a10 = __builtin_amdgcn_mfma_f64_16x16x4f64(xa1,cb0,a10,0,0,0);
            a11 = __builtin_amdgcn_mfma_f64_16x16x4f64(xa1,cb1,a11,0,0,0);
        }
        #pragma unroll
        for (int i=0;i<4;i++){
            int s0 = sBase + wc + pn[i];
            int s1 = s0 + 16;
            if (s0 < SS){
                double z = sgn*a00[i];
                if (z > bz[0][0][i]){ bz[0][0][i] = z; bs[0][0][i] = s0; }
                z = sgn*a10[i];
                if (z > bz[1][0][i]){ bz[1][0][i] = z; bs[1][0][i] = s0; }
            }
            if (s1 < SS){
                double z = sgn*a01[i];
                if (z > bz[0][1][i]){ bz[0][1][i] = z; bs[0][1][i] = s1; }
                z = sgn*a11[i];
                if (z > bz[1][1][i]){ bz[1][1][i] = z; bs[1][1][i] = s1; }
            }
        }
    }
    __syncthreads();
    double* redv = &xs[0][0];
    int*    redi = (int*)&cs[0][0];
    #pragma unroll
    for (int rf=0; rf<2; rf++){
        #pragma unroll
        for (int i=0;i<4;i++){
            double z0 = bz[rf][0][i]; int i0 = bs[rf][0][i];
            double z1 = bz[rf][1][i]; int i1 = bs[rf][1][i];
            bool take1 = (z1 > z0) || (z1 == z0 && i1 < i0);
            double z = take1 ? z1 : z0;
            int    s = take1 ? i1 : i0;
            int row = wr + rf*16 + pm[i];
            int cls = (w & 1)*16 + pn[i];
            redv[row*32 + cls] = z;
            redi[row*32 + cls] = s;
        }
    }
    __syncthreads();
    if (t < 64){
        double best = redv[t*32]; int bi = redi[t*32];
        #pragma unroll
        for (int c = 1; c < 32; c++){
            double v = redv[t*32 + c]; int ii = redi[t*32 + c];
            if (v > best || (v == best && ii < bi)){ best = v; bi = ii; }
        }
        int l = lBase + t;
        if (l < LL){
            double nrm = norms[((size_t)nl*FCn + h)*LL + l];
            double zb = alpha*((sgn*best)/nrm) + beta;
            double val;
            if (zb >= 0.0) val = 1.0/(1.0 + exp(-zb));
            else { double e = exp(zb); val = e/(1.0+e); }
            const double* cv = cp + ((size_t)(n*SS + bi))*C2 + h*64 + 32;
            short* dr = dispb + ((size_t)(n*LL + l))*CC + h*SCn;
            #pragma unroll
            for (int k=0;k<32;k++) dr[k] = f2b((float)(val*cv[k]));
        }
    }
}

// ---------------- row LayerNorm f32 -> bf16 (row = 256) ---------------------------------
__global__ __launch_bounds__(256) void ln_bf_k(const float* __restrict__ y,
    const float* __restrict__ g, const float* __restrict__ b, short* __restrict__ ob){
    int row = blockIdx.x*4 + (threadIdx.x >> 6);
    int lane = threadIdx.x & 63;
    const float* rp = y + (size_t)row*CC;
    float4 v = *(const float4*)(rp + lane*4);
    float s = v.x+v.y+v.z+v.w;
    float q = v.x*v.x+v.y*v.y+v.z*v.z+v.w*v.w;
    #pragma unroll
    for (int off = 32; off; off >>= 1){ s += __shfl_xor(s, off); q += __shfl_xor(q, off); }
    float mu = s*(1.0f/CC);
    float var = q*(1.0f/CC) - mu*mu;
    float r = rsqrtf(var + 1e-5f);
    int c = lane*4;
    float4 gv = *(const float4*)(g+c);
    float4 bv = *(const float4*)(b+c);
    short* op = ob + (size_t)row*CC + c;
    op[0] = f2b((v.x-mu)*r*gv.x+bv.x);
    op[1] = f2b((v.y-mu)*r*gv.y+bv.y);
    op[2] = f2b((v.z-mu)*r*gv.z+bv.z);
    op[3] = f2b((v.w-mu)*r*gv.w+bv.w);
}

// ---------------- final: out = LN(out)*g+b + res(f64) -----------------------------------
__global__ __launch_bounds__(256) void final_k(float* __restrict__ y, const double* __restrict__ res,
    const float* __restrict__ g, const float* __restrict__ b){
    int row = blockIdx.x*4 + (threadIdx.x >> 6);
    int lane = threadIdx.x & 63;
    float* rp = y + (size_t)row*CC;
    const double* xp = res + (size_t)row*CC;
    float4 v = *(const float4*)(rp + lane*4);
    float s = v.x+v.y+v.z+v.w;
    float q = v.x*v.x+v.y*v.y+v.z*v.z+v.w*v.w;
    #pragma unroll
    for (int off = 32; off; off >>= 1){ s += __shfl_xor(s, off); q += __shfl_xor(q, off); }
    float mu = s*(1.0f/CC);
    float var = q*(1.0f/CC) - mu*mu;
    float r = rsqrtf(var + 1e-5f);
    int c = lane*4;
    float4 gv = *(const float4*)(g+c);
    float4 bv = *(const float4*)(b+c);
    float4 o;
    o.x = (v.x-mu)*r*gv.x+bv.x + (float)xp[c+0];
    o.y = (v.y-mu)*r*gv.y+bv.y + (float)xp[c+1];
    o.z = (v.z-mu)*r*gv.z+bv.z + (float)xp[c+2];
    o.w = (v.w-mu)*r*gv.w+bv.w + (float)xp[c+3];
    *(float4*)(rp+c) = o;
}

extern "C" void kernel_launch(void* const* d_in, const int* in_sizes, int n_in,
                              void* d_out, int out_size, void* d_ws, size_t ws_size,
                              hipStream_t stream)
{
    const float* x16[2] = {(const float*)d_in[0], (const float*)d_in[1]};
    const float* x32[2] = {(const float*)d_in[2], (const float*)d_in[3]};
    const float* mb_l0_w = (const float*)d_in[6];
    const float* mb_l0_b = (const float*)d_in[7];
    const float* mb_l1_w = (const float*)d_in[8];
    const float* mb_l1_b = (const float*)d_in[9];
    const float* mb_gn_g = (const float*)d_in[10];
    const float* mb_gn_b = (const float*)d_in[11];
    const float* gc_p0_w = (const float*)d_in[12];
    const float* gc_p0_b = (const float*)d_in[13];
    const float* gc_p1_w = (const float*)d_in[14];
    const float* gc_p1_b = (const float*)d_in[15];
    const float* gc_m_w  = (const float*)d_in[16];
    const float* gc_m_b  = (const float*)d_in[17];
    const float* gc_alpha= (const float*)d_in[18];
    const float* gc_beta = (const float*)d_in[19];
    const float* gb_n0_g = (const float*)d_in[20];
    const float* gb_n0_b = (const float*)d_in[21];
    const float* gb_lin_w= (const float*)d_in[22];
    const float* gb_lin_b= (const float*)d_in[23];
    const float* gb_conv_w=(const float*)d_in[24];
    const float* gb_conv_b=(const float*)d_in[25];
    const float* gb_n1_g = (const float*)d_in[26];
    const float* gb_n1_b = (const float*)d_in[27];

    // ---------------- workspace layout (bytes) ----------------
    const size_t F8  = (size_t)M16*CC*8;      // 44,302,336
    const size_t G8  = (size_t)M32*CC*8;      // 11,075,584
    const size_t WT4 = (size_t)KCONV*CC*4;    //  4,718,592

    char* base = (char*)d_ws;
    double* mx[2] = { (double*)base, (double*)(base + F8) };
    double* mc[2] = { (double*)(base + 2*F8), (double*)(base + 2*F8 + G8) };
    char*   pWT   = base + 2*F8 + 2*G8;
    short*  WTb   = (short*)pWT;                       // 2,359,296
    short*  WLb   = (short*)(pWT + 2359296);           //   524,288
    short*  WMb   = (short*)(pWT + 2883584);           //   131,072
    double* stats = (double*)(pWT + WT4);
    char*   E     = pWT + WT4 + 256;
    const size_t base_need = 2*F8 + 2*G8 + WT4 + 256;

    // pick largest chunk size nb in {8,4,2,1} that fits
    const size_t T2  = (size_t)LL*CC*8;   // 5,537,792 per sample (f64, 256-wide)
    const size_t T1  = (size_t)LL*C2*8;   // 11,075,584 per sample (f64, 512-wide)
    const size_t TN  = (size_t)FCn*LL*8;  // 173,056 per sample (norms)
    int nb = 1;
    {
        const int cands[4] = {8,4,2,1};
        for (int ci = 0; ci < 4; ci++){
            int c = cands[ci];
            size_t merge_r  = (size_t)c*(2*T2 + T1);
            size_t global_r = 22151168ull + 11075584ull + (size_t)c*(T2 + TN) + 11075584ull + 11075584ull;
            size_t r = merge_r > global_r ? merge_r : global_r;
            if (base_need + r <= ws_size){ nb = c; break; }
            if (c == 1) return;
        }
    }

    // merge-phase scratch (chunk of nb samples)
    double* t2c = (double*)E;
    double* t1c = (double*)(E + nb*T2);
    double* upc = (double*)(E + nb*(T2 + T1));
    // global-phase scratch
    double* cp    = (double*)E;                                          // 22,151,168
    double* ctn   = (double*)(E + 22151168);                             // 11,075,584
    double* xpc   = (double*)(E + 33226752);                             // nb*T2
    double* norms = (double*)(E + 33226752 + nb*T2);                     // nb*TN
    short*  dispb = (short*) (E + 33226752 + (size_t)nb*(T2 + TN));              // 11,075,584
    short*  mxb   = (short*) (E + 33226752 + (size_t)nb*(T2 + TN) + 11075584);   // 11,075,584
    float*  Dbuf  = (float*) E;                                          // over cp (after sims)
    short*  Dbufb = (short*) (E + 22151168);                             // over ctn (after ln)
    short*  Bbufb = (short*) E;                                          // over Dbuf (after gb_lin)

    wtransb_k<<<CC, C2, 0, stream>>>(gb_conv_w, WTb);
    wtb_k<<<C2, 256, 0, stream>>>(gb_lin_w, WLb, C2, C2);
    wtb_k<<<CC, 256, 0, stream>>>(gc_m_w, WMb, CC, CC);

    const int Mc = nb*LL;
    const int mTiles = (Mc + 63) / 64;

    // -------- merge blocks (f64 MFMA, chunked) --------
    for (int i = 0; i < 2; i++){
        hipMemsetAsync(stats, 0, 16*sizeof(double), stream);
        for (int ch = 0; ch < NB; ch += nb){
            const float* x16c = x16[i] + (size_t)ch*SAMP16;
            const float* x32c = x32[i] + (size_t)ch*SAMP32;
            ups_k<<<nb*LL, 256, 0, stream>>>(x32c, upc);
            gemm_d64<float,double,double,true,true><<<dim3(8, mTiles), 256, 0, stream>>>(
                x16c, upc, CC, mb_l0_w, mb_l0_b, t1c, Mc, C2, C2);
            gemm_d64<double,double,double,false,false><<<dim3(4, mTiles), 256, 0, stream>>>(
                t1c, (const double*)nullptr, C2, mb_l1_w, mb_l1_b, t2c, Mc, C2, CC);
            gn_stats_k<<<dim3(169, nb), 256, 0, stream>>>(t2c, stats, ch);
            merge_x_k<<<nb*LL, 256, 0, stream>>>(t2c, x16c,
                mb_gn_g, mb_gn_b, stats, ch, mx[i] + (size_t)ch*SAMP16);
            merge_c_k<<<nb*SS, 256, 0, stream>>>(t2c, x32c,
                mb_gn_g, mb_gn_b, stats, ch, mc[i] + (size_t)ch*SAMP32);
        }
    }

    // -------- global blocks (f64 pre-sim, bf16-MFMA post-sim) --------
    float* outp[2] = { (float*)d_out, (float*)d_out + (size_t)M16*CC };
    for (int i = 0; i < 2; i++){
        const double* xi64 = mx[i];
        const double* ci64 = mc[1-i];
        gemm_d64<double,double,double,false,false><<<dim3(8, (M32+63)/64), 256, 0, stream>>>(
            ci64, (const double*)nullptr, CC, gc_p1_w, gc_p1_b, cp, M32, CC, C2);
        cptn_k<<<M32, 256, 0, stream>>>(cp, ctn);
        for (int ch = 0; ch < NB; ch += nb){
            gemm_d64<double,double,double,false,false><<<dim3(4, mTiles), 256, 0, stream>>>(
                xi64 + (size_t)ch*SAMP16, (const double*)nullptr, CC, gc_p0_w, gc_p0_b,
                xpc, Mc, CC, CC);
            norm_k<<<dim3(nb*(LL/8), FCn), 256, 0, stream>>>(xpc, norms);
            sim3_k<<<dim3((LL+63)/64, FCn, nb), 256, 0, stream>>>(
                xpc, norms, ctn, cp, gc_alpha, gc_beta, ch, dispb);
        }
        d2b_k<<<(M16*CC)/256, 256, 0, stream>>>(xi64, mxb);
        gemm_bf<false,false,false><<<dim3(4, 338), 256, 0, stream>>>(
            dispb, (const short*)nullptr, CC, WMb, gc_m_b, Dbuf, M16, CC, CC);
        ln_bf_k<<<M16/4, 256, 0, stream>>>(Dbuf, gb_n0_g, gb_n0_b, Dbufb);
        gemm_bf<true,true,true><<<dim3(8, 338), 256, 0, stream>>>(
            mxb, Dbufb, CC, WLb, gb_lin_b, Bbufb, M16, C2, C2);
        conv_bf2<<<M16/32, 256, 0, stream>>>(Bbufb, WTb, gb_conv_b, outp[i]);
        final_k<<<M16/4, 256, 0, stream>>>(outp[i], xi64, gb_n1_g, gb_n1_b);
    }
}